// Round 16
// baseline (1284.025 us; speedup 1.0000x reference)
//
#include <hip/hip_runtime.h>
#include <hip/hip_cooperative_groups.h>
#include <math.h>

namespace cg = cooperative_groups;

// Problem constants
#define BATCH 256
#define IC    1152
#define EDIM  8
#define NC    10
#define DV    16

// Tiling
#define ITILE  8                    // i's covered by thread layout (il = 0..7)
#define NCHUNK 6                    // 24 slabs; grid 24x64 (R9 geometry)
#define ITOT   (ITILE * NCHUNK)     // 48 i's per block
#define NB     4                    // b's per block (R7 lesson: keep 4)
#define NTHREADS 256                // 16 d * 2 il_lo * 2 ch * 4 il_hi
#define NWAVES 4
#define NSLAB  (IC / ITOT)          // 24 partial slabs
#define BCHUNKS (BATCH / NB)        // 64
#define SCD (NC * DV)               // 160
#define SPART_STRIDE (BATCH * SCD)  // 40960 floats per slab
#define SPART_F4     (SPART_STRIDE / 4)   // 10240 float4 per slab
#define L2E 1.4426950408889634f
#define XF4_TOT (NB * ITOT * EDIM / 4)   // 384 float4 of x per block
#define XF4_ROW (ITOT * EDIM / 4)        // 96 float4 per b row
#define WXU     2560                      // float4 per (icb,ic) unit
#define NBLOCKS_P 768                     // persistent grid: 2 units/block

typedef float v2f __attribute__((ext_vector_type(2)));
typedef float v4f __attribute__((ext_vector_type(4)));

// ---------------------------------------------------------------------------
// DPP-based reduces — all VALU. MUST stay on __builtin_amdgcn_update_dpp
// (R2: inline-asm DPP skipped hazard nops -> silent corruption).
// ---------------------------------------------------------------------------
template<int CTRL>
__device__ __forceinline__ float dpp_add(float x) {
    int r = __builtin_amdgcn_update_dpp(0, __float_as_int(x), CTRL, 0xF, 0xF, true);
    return x + __int_as_float(r);
}
__device__ __forceinline__ float row_reduce16(float x) {
    x = dpp_add<0xB1>(x);   // xor 1
    x = dpp_add<0x4E>(x);   // xor 2
    x = dpp_add<0x141>(x);  // xor 4
    x = dpp_add<0x140>(x);  // xor 8
    return x;
}
__device__ __forceinline__ float quad_reduce4(float x) {
    x = dpp_add<0xB1>(x);
    x = dpp_add<0x4E>(x);
    return x;
}

typedef int int2v __attribute__((ext_vector_type(2)));
#if __has_builtin(__builtin_amdgcn_permlane32_swap)
__device__ __forceinline__ float cross32_sum(float x) {
    int2v r = __builtin_amdgcn_permlane32_swap(__float_as_int(x), __float_as_int(x),
                                               false, false);
    return __int_as_float(r[0]) + __int_as_float(r[1]);
}
#else
__device__ __forceinline__ float cross32_sum(float x) { return x + __shfl_xor(x, 32); }
#endif

#if __has_builtin(__builtin_amdgcn_exp2f)
#define EXP2F(x) __builtin_amdgcn_exp2f(x)
#else
#define EXP2F(x) exp2f(x)
#endif

// v_pk_fma_f32 packed dot (R6-proven)
__device__ __forceinline__ float dot8_pk(v4f w0, v4f w1, v4f x0, v4f x1) {
    v2f a =  __builtin_shufflevector(w0, w0, 0, 1) * __builtin_shufflevector(x0, x0, 0, 1);
    a = __builtin_elementwise_fma(__builtin_shufflevector(w0, w0, 2, 3),
                                  __builtin_shufflevector(x0, x0, 2, 3), a);
    a = __builtin_elementwise_fma(__builtin_shufflevector(w1, w1, 0, 1),
                                  __builtin_shufflevector(x1, x1, 0, 1), a);
    a = __builtin_elementwise_fma(__builtin_shufflevector(w1, w1, 2, 3),
                                  __builtin_shufflevector(x1, x1, 2, 3), a);
    return a[0] + a[1];
}

// ---------------------------------------------------------------------------
// W -> wave-fragment-major Wt, LDS-TILED (R11-proven, -15% in caps_main).
// Separate dispatch (40KB LDS won't fit the persistent residency budget).
// ---------------------------------------------------------------------------
__global__ __launch_bounds__(256)
void caps_wxform(const float4* __restrict__ W4, float4* __restrict__ Wt)
{
    __shared__ float4 lds[WXU];              // 40 KB
    const int tid = threadIdx.x;
    const size_t base = (size_t)blockIdx.x * WXU;   // unit = icb*6+ic

    #pragma unroll
    for (int t = 0; t < WXU / 256; ++t)
        lds[t * 256 + tid] = W4[base + t * 256 + tid];
    __syncthreads();
    #pragma unroll
    for (int t = 0; t < WXU / 256; ++t) {
        int lo   = t * 256 + tid;
        int wid  = lo / 640;
        int r0   = lo - wid * 640;
        int kk   = r0 >> 7;                  // 0..4
        int r1   = r0 & 127;
        int h    = r1 >> 6;
        int ch   = (r1 >> 5) & 1;
        int il_lo= (r1 >> 4) & 1;
        int d    = r1 & 15;
        int il   = wid * 2 + il_lo;
        int c    = ch * 5 + kk;
        Wt[base + lo] = lds[il * 320 + c * 32 + d * 2 + h];
    }
}

// ---------------------------------------------------------------------------
// Main phase — EXACT R11/R14 caps_main body (42.5-44.9us measured, VGPR 64).
// LANE MAP: d = bits0-3, il_lo = bit4, ch = bit5, il_hi = bits6-7 (== wid).
// MODE 1: c = softmax(bias)                              -> s1 partials
// MODE 2: b2 = L2E*(u.v1) + 2*L2E*bias (stored), softmax -> s2 partials
// MODE 3: b3 = L2E*(u.v2) + b2 + L2E*bias, softmax       -> s3 partials
// ---------------------------------------------------------------------------
template<int MODE>
__device__ void main_phase(const float* __restrict__ x,
                           const v4f* __restrict__ Wt,
                           const float* __restrict__ bias,
                           const float* __restrict__ v_in,   // L2E-scaled
                           float* __restrict__ b2,
                           float* __restrict__ s_part,
                           int icb, int bcb,
                           float (*sx)[ITOT * EDIM],
                           float (*swv)[NB][SCD],
                           float (*vls)[SCD])
{
    const int tid = threadIdx.x;
    const int d   = tid & 15;
    const int ch  = (tid >> 5) & 1;                       // lane bit 5
    const int il  = ((tid >> 4) & 1) | (((tid >> 6) & 3) << 1);
    const int wid = tid >> 6;                // 0..3
    const int i0  = icb * ITOT;
    const int b0  = bcb * NB;

    // ---- stage x slice: 384 float4, coalesced ----
    {
        const float4* xg = (const float4*)x;
        float4* xs = (float4*)&sx[0][0];
        #pragma unroll
        for (int t = 0; t < 2; ++t) {
            int idx = t * NTHREADS + tid;
            if (idx < XF4_TOT) {
                int bb = idx / XF4_ROW;
                int w  = idx - bb * XF4_ROW;
                xs[idx] = xg[(size_t)(b0 + bb) * (IC * EDIM / 4)
                             + i0 * (EDIM / 4) + w];
            }
        }
    }
    // ---- stage v tile (640 floats, coalesced) ----
    if (MODE != 1) {
        #pragma unroll
        for (int t = 0; t < 3; ++t) {
            int j = t * NTHREADS + tid;
            if (j < NB * SCD)
                (&vls[0][0])[j] = v_in[(size_t)b0 * SCD + j];
        }
    }

    float sacc[NB][5];
    #pragma unroll
    for (int bb = 0; bb < NB; ++bb)
        #pragma unroll
        for (int k = 0; k < 5; ++k) sacc[bb][k] = 0.f;

    __syncthreads();

    // per-wave Wt base for this block (chunk 0): lane-resolved
    const v4f* wpb = Wt + (size_t)((icb * NCHUNK) * NWAVES + wid) * 640
                        + (tid & 63);

    #pragma unroll 1
    for (int ic = 0; ic < NCHUNK; ++ic) {
        const int i = i0 + ic * ITILE + il;
        const v4f* wp = wpb + (size_t)ic * (NWAVES * 640);

        // W fragment (contiguous 1KB wave-loads) + bias for this i-chunk
        v4f   w4[5][2];
        float bv[5];
        #pragma unroll
        for (int k = 0; k < 5; ++k) {
            w4[k][0] = wp[(k * 2 + 0) * 64];
            w4[k][1] = wp[(k * 2 + 1) * 64];
            bv[k]    = bias[i * NC + ch * 5 + k];
        }

        float cw[5];
        float bvs[5];
        if (MODE == 1) {
            // softmax(bias[i,:]) — batch-independent, once per i-chunk
            float ssum = 0.f, ex[5];
            #pragma unroll
            for (int k = 0; k < 5; ++k) { ex[k] = __expf(bv[k]); ssum += ex[k]; }
            ssum = cross32_sum(ssum);
            float inv = __builtin_amdgcn_rcpf(ssum);
            #pragma unroll
            for (int k = 0; k < 5; ++k) cw[k] = ex[k] * inv;
        } else {
            #pragma unroll
            for (int k = 0; k < 5; ++k) bvs[k] = bv[k] * L2E;
        }

        #pragma unroll
        for (int bb = 0; bb < NB; ++bb) {
            const int b = b0 + bb;
            const v4f x0 = ((const v4f*)&sx[bb][(ic * ITILE + il) * EDIM])[0];
            const v4f x1 = ((const v4f*)&sx[bb][(ic * ITILE + il) * EDIM])[1];

            // u_hat[b, i, c_k, d] — packed-pair dot (v_pk_fma_f32)
            float u[5];
            #pragma unroll
            for (int k = 0; k < 5; ++k)
                u[k] = dot8_pk(w4[k][0], w4[k][1], x0, x1);

            if (MODE != 1) {
                // agreement (L2E-scaled via v): sum over d via DPP row reduce
                const float* vb = &vls[bb][ch * 80 + d];
                float t[5];
                #pragma unroll
                for (int k = 0; k < 5; ++k) t[k] = u[k] * vb[k * 16];
                #pragma unroll
                for (int k = 0; k < 5; ++k) t[k] = row_reduce16(t[k]);

                float br[5];
                float* bp = b2 + (((size_t)b * IC + i) * 2 + ch) * 8;  // padded
                if (MODE == 2) {
                    #pragma unroll
                    for (int k = 0; k < 5; ++k) br[k] = fmaf(2.0f, bvs[k], t[k]);
                    if (d == 0) {
                        #pragma unroll
                        for (int k = 0; k < 5; ++k) bp[k] = br[k];
                    }
                } else {
                    #pragma unroll
                    for (int k = 0; k < 5; ++k) br[k] = t[k] + bp[k] + bvs[k];
                }
                // softmax over 10 c's: 5 local + partner half via permlane32.
                // Logits are log2-domain -> raw v_exp_f32, no max-pass.
                float ssum = 0.f, ex[5];
                #pragma unroll
                for (int k = 0; k < 5; ++k) { ex[k] = EXP2F(br[k]); ssum += ex[k]; }
                ssum = cross32_sum(ssum);
                float inv = __builtin_amdgcn_rcpf(ssum);
                #pragma unroll
                for (int k = 0; k < 5; ++k) cw[k] = ex[k] * inv;
            }

            // register s-accumulation — no LDS, no shuffle, no barrier
            #pragma unroll
            for (int k = 0; k < 5; ++k)
                sacc[bb][k] = fmaf(cw[k], u[k], sacc[bb][k]);
        }
    }

    // ---- epilogue: il-pair reduce + wave slabs + 4-way reduce + flush ----
    #pragma unroll
    for (int bb = 0; bb < NB; ++bb) {
        #pragma unroll
        for (int k = 0; k < 5; ++k) {
            float s = sacc[bb][k] + __shfl_xor(sacc[bb][k], 16);
            if ((tid & 16) == 0)
                swv[wid][bb][ch * 80 + k * 16 + d] = s;
        }
    }
    __syncthreads();
    for (int j = tid; j < NB * SCD; j += NTHREADS) {    // 640 elems
        int bb = j / SCD;
        int cd = j - bb * SCD;
        float s = (swv[0][bb][cd] + swv[1][bb][cd])
                + (swv[2][bb][cd] + swv[3][bb][cd]);
        s_part[((size_t)icb * BATCH + b0 + bb) * SCD + cd] = s;
    }
}

// ---------------------------------------------------------------------------
// Squash phase — EXACT R14 body (f4-wide, slab-split across 4 thread-
// groups + LDS combine + quad-DPP). mult = L2E (intermediate) / 1.0 (out).
// ---------------------------------------------------------------------------
__device__ void squash_phase(const float* __restrict__ s_part,
                             float* __restrict__ outp, float mult,
                             int bid, v4f (*part)[64])
{
    const int tid = threadIdx.x;
    const int f   = tid & 63;
    const int q   = tid >> 6;
    const int g   = bid * 64 + f;                      // f4 index, 0..10239

    const v4f* sp = (const v4f*)s_part + g;
    v4f a = {0.f, 0.f, 0.f, 0.f};
    #pragma unroll
    for (int j = 0; j < 6; ++j)                        // slabs q*6 .. q*6+5
        a += sp[(size_t)(q * 6 + j) * SPART_F4];
    part[q][f] = a;
    __syncthreads();

    if (tid < 64) {
        v4f s4 = (part[0][tid] + part[1][tid]) + (part[2][tid] + part[3][tid]);
        float sq = (s4[0]*s4[0] + s4[1]*s4[1]) + (s4[2]*s4[2] + s4[3]*s4[3]);
        sq = quad_reduce4(sq);
        float scale = mult * sq / ((1.0f + sq) * sqrtf(sq + 1e-7f));
        ((v4f*)outp)[bid * 64 + tid] = scale * s4;
    }
}

// ---------------------------------------------------------------------------
// R16 persistent kernel — grid 768 (2 units/block, 3 blocks/CU needed vs
// ~6 capacity: 2x residency margin; R15's 1536 sat at exactly 100% and
// the launch silently failed -> all-zero output, absmax 0.797 = max|ref|).
// Units bid and bid+768 share icb (768%24==0): same W slice (L2-hot 2nd
// pass), R9 XCD affinity preserved (blocks sharing icb differ by 24 ->
// same bid%8). Explicit __threadfence() before each grid.sync as
// coherence insurance.
// ---------------------------------------------------------------------------
__global__ __launch_bounds__(NTHREADS, 6)
void caps_persist(const float* __restrict__ x,
                  const v4f* __restrict__ Wt,
                  const float* __restrict__ bias,
                  float* __restrict__ v,
                  float* __restrict__ b2,
                  float* __restrict__ s_part,
                  float* __restrict__ out)
{
    __shared__ float sx[NB][ITOT * EDIM];    // 6 KB
    __shared__ float swv[NWAVES][NB][SCD];   // 10 KB
    __shared__ float vls[NB][SCD];           // 2.5 KB
    __shared__ v4f  part[4][64];             // 4 KB  (squash phases)

    cg::grid_group grid = cg::this_grid();
    const int bid  = blockIdx.x;
    const int icb  = bid % NSLAB;            // fast axis — XCD map preserved
    const int bcb0 = bid / NSLAB;            // 0..31
    const int bcb1 = bcb0 + (NBLOCKS_P / NSLAB);   // 32..63

    // iter 1
    main_phase<1>(x, Wt, bias, nullptr, b2, s_part, icb, bcb0, sx, swv, vls);
    __syncthreads();
    main_phase<1>(x, Wt, bias, nullptr, b2, s_part, icb, bcb1, sx, swv, vls);
    __threadfence();
    grid.sync();
    if (bid < 160) squash_phase(s_part, v, L2E, bid, part);
    __threadfence();
    grid.sync();
    // iter 2
    main_phase<2>(x, Wt, bias, v, b2, s_part, icb, bcb0, sx, swv, vls);
    __syncthreads();
    main_phase<2>(x, Wt, bias, v, b2, s_part, icb, bcb1, sx, swv, vls);
    __threadfence();
    grid.sync();
    if (bid < 160) squash_phase(s_part, v, L2E, bid, part);
    __threadfence();
    grid.sync();
    // iter 3
    main_phase<3>(x, Wt, bias, v, b2, s_part, icb, bcb0, sx, swv, vls);
    __syncthreads();
    main_phase<3>(x, Wt, bias, v, b2, s_part, icb, bcb1, sx, swv, vls);
    __threadfence();
    grid.sync();
    if (bid < 160) squash_phase(s_part, out, 1.0f, bid, part);
}

// ---------------------------------------------------------------------------
// Fallback path (R14, proven passing at 164.7us): standalone main + squash.
// ---------------------------------------------------------------------------
template<int MODE>
__global__ __launch_bounds__(NTHREADS, 2)
void caps_main(const float* __restrict__ x,
               const v4f* __restrict__ Wt,
               const float* __restrict__ bias,
               const float* __restrict__ v_in,
               float* __restrict__ b2,
               float* __restrict__ s_part)
{
    __shared__ float sx[NB][ITOT * EDIM];
    __shared__ float swv[NWAVES][NB][SCD];
    __shared__ float vls[NB][SCD];
    main_phase<MODE>(x, Wt, bias, v_in, b2, s_part,
                     blockIdx.x, blockIdx.y, sx, swv, vls);
}

__global__ __launch_bounds__(256)
void caps_squash(const float* __restrict__ s_part, float* __restrict__ out,
                 float mult)
{
    __shared__ v4f part[4][64];
    squash_phase(s_part, out, mult, blockIdx.x, part);
}

// ---------------------------------------------------------------------------
extern "C" void kernel_launch(void* const* d_in, const int* in_sizes, int n_in,
                              void* d_out, int out_size, void* d_ws, size_t ws_size,
                              hipStream_t stream)
{
    const float* x    = (const float*)d_in[0];   // [256,1152,8]
    const float* W    = (const float*)d_in[1];   // [1152,10,16,8]
    const float* bias = (const float*)d_in[2];   // [1152,10]
    float* out = (float*)d_out;                  // [256,10,16]

    float* ws     = (float*)d_ws;
    float* s_part = ws;                                       // 24*40960 = 983,040 f
    float* v      = s_part + (size_t)NSLAB * SPART_STRIDE;    // 40,960 f (L2E-scaled)
    float* b2     = v + SPART_STRIDE;                         // padded: 4,718,592 f
    float* wt     = b2 + (size_t)BATCH * IC * 16;             // 1,474,560 f (5.9 MB)
    // total ws use: ~29 MB

    // W layout transform (separate dispatch; 40KB LDS)
    caps_wxform<<<NSLAB * NCHUNK, 256, 0, stream>>>((const float4*)W, (float4*)wt);

    // ---- guarded cooperative attempt ----
    bool coop = false;
    {
        int maxb = 0;
        if (hipOccupancyMaxActiveBlocksPerMultiprocessor(&maxb, caps_persist,
                                                         NTHREADS, 0) == hipSuccess
            && maxb * 256 >= NBLOCKS_P) {
            const v4f* wtp = (const v4f*)wt;
            void* kargs[] = { (void*)&x, (void*)&wtp, (void*)&bias,
                              (void*)&v, (void*)&b2, (void*)&s_part, (void*)&out };
            if (hipLaunchCooperativeKernel((void*)caps_persist,
                                           dim3(NBLOCKS_P), dim3(NTHREADS),
                                           kargs, 0, stream) == hipSuccess)
                coop = true;
        }
    }

    if (!coop) {
        // R14 multi-dispatch fallback (proven: 164.7us, absmax 0.00195)
        dim3 grid(NSLAB, BCHUNKS);   // icb fast (R5/R9)
        caps_main<1><<<grid, NTHREADS, 0, stream>>>(x, (const v4f*)wt, bias, v, b2, s_part);
        caps_squash<<<160, 256, 0, stream>>>(s_part, v, L2E);
        caps_main<2><<<grid, NTHREADS, 0, stream>>>(x, (const v4f*)wt, bias, v, b2, s_part);
        caps_squash<<<160, 256, 0, stream>>>(s_part, v, L2E);
        caps_main<3><<<grid, NTHREADS, 0, stream>>>(x, (const v4f*)wt, bias, v, b2, s_part);
        caps_squash<<<160, 256, 0, stream>>>(s_part, out, 1.0f);
    }
}

// Round 17
// 167.693 us; speedup vs baseline: 7.6570x; 7.6570x over previous
//
#include <hip/hip_runtime.h>
#include <hip/hip_cooperative_groups.h>
#include <math.h>

namespace cg = cooperative_groups;

// Problem constants
#define BATCH 256
#define IC    1152
#define EDIM  8
#define NC    10
#define DV    16

// Tiling
#define ITILE  8                    // i's covered by thread layout (il = 0..7)
#define NCHUNK 6                    // 24 slabs; grid 24x64 (R9 geometry)
#define ITOT   (ITILE * NCHUNK)     // 48 i's per block
#define NB     4                    // b's per block (R7 lesson: keep 4)
#define NTHREADS 256                // 16 d * 2 il_lo * 2 ch * 4 il_hi
#define NWAVES 4
#define NSLAB  (IC / ITOT)          // 24 partial slabs
#define BCHUNKS (BATCH / NB)        // 64
#define SCD (NC * DV)               // 160
#define SPART_STRIDE (BATCH * SCD)  // 40960 floats per slab
#define SPART_F4     (SPART_STRIDE / 4)   // 10240 float4 per slab
#define L2E 1.4426950408889634f
#define XF4_TOT (NB * ITOT * EDIM / 4)   // 384 float4 of x per block
#define XF4_ROW (ITOT * EDIM / 4)        // 96 float4 per b row
#define WXU     2560                      // float4 per (icb,ic) unit
#define NBLOCKS_P 768                     // persistent grid: 2 units/block

typedef float v2f __attribute__((ext_vector_type(2)));
typedef float v4f __attribute__((ext_vector_type(4)));

// ---------------------------------------------------------------------------
// DPP-based reduces — all VALU. MUST stay on __builtin_amdgcn_update_dpp
// (R2: inline-asm DPP skipped hazard nops -> silent corruption).
// ---------------------------------------------------------------------------
template<int CTRL>
__device__ __forceinline__ float dpp_add(float x) {
    int r = __builtin_amdgcn_update_dpp(0, __float_as_int(x), CTRL, 0xF, 0xF, true);
    return x + __int_as_float(r);
}
__device__ __forceinline__ float row_reduce16(float x) {
    x = dpp_add<0xB1>(x);   // xor 1
    x = dpp_add<0x4E>(x);   // xor 2
    x = dpp_add<0x141>(x);  // xor 4
    x = dpp_add<0x140>(x);  // xor 8
    return x;
}
__device__ __forceinline__ float quad_reduce4(float x) {
    x = dpp_add<0xB1>(x);
    x = dpp_add<0x4E>(x);
    return x;
}

typedef int int2v __attribute__((ext_vector_type(2)));
#if __has_builtin(__builtin_amdgcn_permlane32_swap)
__device__ __forceinline__ float cross32_sum(float x) {
    int2v r = __builtin_amdgcn_permlane32_swap(__float_as_int(x), __float_as_int(x),
                                               false, false);
    return __int_as_float(r[0]) + __int_as_float(r[1]);
}
#else
__device__ __forceinline__ float cross32_sum(float x) { return x + __shfl_xor(x, 32); }
#endif

#if __has_builtin(__builtin_amdgcn_exp2f)
#define EXP2F(x) __builtin_amdgcn_exp2f(x)
#else
#define EXP2F(x) exp2f(x)
#endif

// v_pk_fma_f32 packed dot (R6-proven)
__device__ __forceinline__ float dot8_pk(v4f w0, v4f w1, v4f x0, v4f x1) {
    v2f a =  __builtin_shufflevector(w0, w0, 0, 1) * __builtin_shufflevector(x0, x0, 0, 1);
    a = __builtin_elementwise_fma(__builtin_shufflevector(w0, w0, 2, 3),
                                  __builtin_shufflevector(x0, x0, 2, 3), a);
    a = __builtin_elementwise_fma(__builtin_shufflevector(w1, w1, 0, 1),
                                  __builtin_shufflevector(x1, x1, 0, 1), a);
    a = __builtin_elementwise_fma(__builtin_shufflevector(w1, w1, 2, 3),
                                  __builtin_shufflevector(x1, x1, 2, 3), a);
    return a[0] + a[1];
}

// ---------------------------------------------------------------------------
// W -> wave-fragment-major Wt, LDS-TILED (R11-proven, -15% in caps_main).
// Separate dispatch (40KB LDS won't fit the persistent residency budget).
// ---------------------------------------------------------------------------
__global__ __launch_bounds__(256)
void caps_wxform(const float4* __restrict__ W4, float4* __restrict__ Wt)
{
    __shared__ float4 lds[WXU];              // 40 KB
    const int tid = threadIdx.x;
    const size_t base = (size_t)blockIdx.x * WXU;   // unit = icb*6+ic

    #pragma unroll
    for (int t = 0; t < WXU / 256; ++t)
        lds[t * 256 + tid] = W4[base + t * 256 + tid];
    __syncthreads();
    #pragma unroll
    for (int t = 0; t < WXU / 256; ++t) {
        int lo   = t * 256 + tid;
        int wid  = lo / 640;
        int r0   = lo - wid * 640;
        int kk   = r0 >> 7;                  // 0..4
        int r1   = r0 & 127;
        int h    = r1 >> 6;
        int ch   = (r1 >> 5) & 1;
        int il_lo= (r1 >> 4) & 1;
        int d    = r1 & 15;
        int il   = wid * 2 + il_lo;
        int c    = ch * 5 + kk;
        Wt[base + lo] = lds[il * 320 + c * 32 + d * 2 + h];
    }
}

// ---------------------------------------------------------------------------
// Main phase — EXACT R11/R14 caps_main body (42.5-44.9us, VGPR 64).
// __forceinline__ IS LOAD-BEARING: R16 left this un-inlined; the compiler
// outlined it as an ABI call, put sacc/w4 in SCRATCH (VGPR_Count 40,
// 1.6 GB of spill traffic per dispatch) -> 1262us. Do not remove.
// LANE MAP: d = bits0-3, il_lo = bit4, ch = bit5, il_hi = bits6-7 (== wid).
// MODE 1: c = softmax(bias)                              -> s1 partials
// MODE 2: b2 = L2E*(u.v1) + 2*L2E*bias (stored), softmax -> s2 partials
// MODE 3: b3 = L2E*(u.v2) + b2 + L2E*bias, softmax       -> s3 partials
// ---------------------------------------------------------------------------
template<int MODE>
__device__ __forceinline__
void main_phase(const float* __restrict__ x,
                const v4f* __restrict__ Wt,
                const float* __restrict__ bias,
                const float* __restrict__ v_in,   // L2E-scaled
                float* __restrict__ b2,
                float* __restrict__ s_part,
                int icb, int bcb,
                float (*sx)[ITOT * EDIM],
                float (*swv)[NB][SCD],
                float (*vls)[SCD])
{
    const int tid = threadIdx.x;
    const int d   = tid & 15;
    const int ch  = (tid >> 5) & 1;                       // lane bit 5
    const int il  = ((tid >> 4) & 1) | (((tid >> 6) & 3) << 1);
    const int wid = tid >> 6;                // 0..3
    const int i0  = icb * ITOT;
    const int b0  = bcb * NB;

    // ---- stage x slice: 384 float4, coalesced ----
    {
        const float4* xg = (const float4*)x;
        float4* xs = (float4*)&sx[0][0];
        #pragma unroll
        for (int t = 0; t < 2; ++t) {
            int idx = t * NTHREADS + tid;
            if (idx < XF4_TOT) {
                int bb = idx / XF4_ROW;
                int w  = idx - bb * XF4_ROW;
                xs[idx] = xg[(size_t)(b0 + bb) * (IC * EDIM / 4)
                             + i0 * (EDIM / 4) + w];
            }
        }
    }
    // ---- stage v tile (640 floats, coalesced) ----
    if (MODE != 1) {
        #pragma unroll
        for (int t = 0; t < 3; ++t) {
            int j = t * NTHREADS + tid;
            if (j < NB * SCD)
                (&vls[0][0])[j] = v_in[(size_t)b0 * SCD + j];
        }
    }

    float sacc[NB][5];
    #pragma unroll
    for (int bb = 0; bb < NB; ++bb)
        #pragma unroll
        for (int k = 0; k < 5; ++k) sacc[bb][k] = 0.f;

    __syncthreads();

    // per-wave Wt base for this block (chunk 0): lane-resolved
    const v4f* wpb = Wt + (size_t)((icb * NCHUNK) * NWAVES + wid) * 640
                        + (tid & 63);

    #pragma unroll 1
    for (int ic = 0; ic < NCHUNK; ++ic) {
        const int i = i0 + ic * ITILE + il;
        const v4f* wp = wpb + (size_t)ic * (NWAVES * 640);

        // W fragment (contiguous 1KB wave-loads) + bias for this i-chunk
        v4f   w4[5][2];
        float bv[5];
        #pragma unroll
        for (int k = 0; k < 5; ++k) {
            w4[k][0] = wp[(k * 2 + 0) * 64];
            w4[k][1] = wp[(k * 2 + 1) * 64];
            bv[k]    = bias[i * NC + ch * 5 + k];
        }

        float cw[5];
        float bvs[5];
        if (MODE == 1) {
            // softmax(bias[i,:]) — batch-independent, once per i-chunk
            float ssum = 0.f, ex[5];
            #pragma unroll
            for (int k = 0; k < 5; ++k) { ex[k] = __expf(bv[k]); ssum += ex[k]; }
            ssum = cross32_sum(ssum);
            float inv = __builtin_amdgcn_rcpf(ssum);
            #pragma unroll
            for (int k = 0; k < 5; ++k) cw[k] = ex[k] * inv;
        } else {
            #pragma unroll
            for (int k = 0; k < 5; ++k) bvs[k] = bv[k] * L2E;
        }

        #pragma unroll
        for (int bb = 0; bb < NB; ++bb) {
            const int b = b0 + bb;
            const v4f x0 = ((const v4f*)&sx[bb][(ic * ITILE + il) * EDIM])[0];
            const v4f x1 = ((const v4f*)&sx[bb][(ic * ITILE + il) * EDIM])[1];

            // u_hat[b, i, c_k, d] — packed-pair dot (v_pk_fma_f32)
            float u[5];
            #pragma unroll
            for (int k = 0; k < 5; ++k)
                u[k] = dot8_pk(w4[k][0], w4[k][1], x0, x1);

            if (MODE != 1) {
                // agreement (L2E-scaled via v): sum over d via DPP row reduce
                const float* vb = &vls[bb][ch * 80 + d];
                float t[5];
                #pragma unroll
                for (int k = 0; k < 5; ++k) t[k] = u[k] * vb[k * 16];
                #pragma unroll
                for (int k = 0; k < 5; ++k) t[k] = row_reduce16(t[k]);

                float br[5];
                float* bp = b2 + (((size_t)b * IC + i) * 2 + ch) * 8;  // padded
                if (MODE == 2) {
                    #pragma unroll
                    for (int k = 0; k < 5; ++k) br[k] = fmaf(2.0f, bvs[k], t[k]);
                    if (d == 0) {
                        #pragma unroll
                        for (int k = 0; k < 5; ++k) bp[k] = br[k];
                    }
                } else {
                    #pragma unroll
                    for (int k = 0; k < 5; ++k) br[k] = t[k] + bp[k] + bvs[k];
                }
                // softmax over 10 c's: 5 local + partner half via permlane32.
                // Logits are log2-domain -> raw v_exp_f32, no max-pass.
                float ssum = 0.f, ex[5];
                #pragma unroll
                for (int k = 0; k < 5; ++k) { ex[k] = EXP2F(br[k]); ssum += ex[k]; }
                ssum = cross32_sum(ssum);
                float inv = __builtin_amdgcn_rcpf(ssum);
                #pragma unroll
                for (int k = 0; k < 5; ++k) cw[k] = ex[k] * inv;
            }

            // register s-accumulation — no LDS, no shuffle, no barrier
            #pragma unroll
            for (int k = 0; k < 5; ++k)
                sacc[bb][k] = fmaf(cw[k], u[k], sacc[bb][k]);
        }
    }

    // ---- epilogue: il-pair reduce + wave slabs + 4-way reduce + flush ----
    #pragma unroll
    for (int bb = 0; bb < NB; ++bb) {
        #pragma unroll
        for (int k = 0; k < 5; ++k) {
            float s = sacc[bb][k] + __shfl_xor(sacc[bb][k], 16);
            if ((tid & 16) == 0)
                swv[wid][bb][ch * 80 + k * 16 + d] = s;
        }
    }
    __syncthreads();
    for (int j = tid; j < NB * SCD; j += NTHREADS) {    // 640 elems
        int bb = j / SCD;
        int cd = j - bb * SCD;
        float s = (swv[0][bb][cd] + swv[1][bb][cd])
                + (swv[2][bb][cd] + swv[3][bb][cd]);
        s_part[((size_t)icb * BATCH + b0 + bb) * SCD + cd] = s;
    }
}

// ---------------------------------------------------------------------------
// Squash phase — EXACT R14 body (f4-wide, slab-split across 4 thread-
// groups + LDS combine + quad-DPP). __forceinline__ (R16 lesson).
// mult = L2E (intermediate) / 1.0 (final out).
// ---------------------------------------------------------------------------
__device__ __forceinline__
void squash_phase(const float* __restrict__ s_part,
                  float* __restrict__ outp, float mult,
                  int bid, v4f (*part)[64])
{
    const int tid = threadIdx.x;
    const int f   = tid & 63;
    const int q   = tid >> 6;
    const int g   = bid * 64 + f;                      // f4 index, 0..10239

    const v4f* sp = (const v4f*)s_part + g;
    v4f a = {0.f, 0.f, 0.f, 0.f};
    #pragma unroll
    for (int j = 0; j < 6; ++j)                        // slabs q*6 .. q*6+5
        a += sp[(size_t)(q * 6 + j) * SPART_F4];
    part[q][f] = a;
    __syncthreads();

    if (tid < 64) {
        v4f s4 = (part[0][tid] + part[1][tid]) + (part[2][tid] + part[3][tid]);
        float sq = (s4[0]*s4[0] + s4[1]*s4[1]) + (s4[2]*s4[2] + s4[3]*s4[3]);
        sq = quad_reduce4(sq);
        float scale = mult * sq / ((1.0f + sq) * sqrtf(sq + 1e-7f));
        ((v4f*)outp)[bid * 64 + tid] = scale * s4;
    }
}

// ---------------------------------------------------------------------------
// R17 persistent kernel. Grid 768 (2 units/block; units share icb -> same
// W slice, R9 XCD affinity preserved). __launch_bounds__(256,3): only 3
// blocks/CU of residency needed (vs 7 LDS-capacity) -> VGPR cap 170,
// plenty for the ~64-100 the inlined phases need (R16's (256,6)+outline
// combo caused the scratch catastrophe).
// R15 lesson: grid 1536 = 100% residency -> launch rejected. R16 lesson:
// un-inlined phases -> scratch spill, 1262us. Host guard + R14 fallback
// retained: worst case is the proven 164.7us pipeline.
// ---------------------------------------------------------------------------
__global__ __launch_bounds__(NTHREADS, 3)
void caps_persist(const float* __restrict__ x,
                  const v4f* __restrict__ Wt,
                  const float* __restrict__ bias,
                  float* __restrict__ v,
                  float* __restrict__ b2,
                  float* __restrict__ s_part,
                  float* __restrict__ out)
{
    __shared__ float sx[NB][ITOT * EDIM];    // 6 KB
    __shared__ float swv[NWAVES][NB][SCD];   // 10 KB
    __shared__ float vls[NB][SCD];           // 2.5 KB
    __shared__ v4f  part[4][64];             // 4 KB  (squash phases)

    cg::grid_group grid = cg::this_grid();
    const int bid  = blockIdx.x;
    const int icb  = bid % NSLAB;            // fast axis — XCD map preserved
    const int bcb0 = bid / NSLAB;            // 0..31
    const int bcb1 = bcb0 + (NBLOCKS_P / NSLAB);   // 32..63

    // iter 1
    main_phase<1>(x, Wt, bias, nullptr, b2, s_part, icb, bcb0, sx, swv, vls);
    __syncthreads();
    main_phase<1>(x, Wt, bias, nullptr, b2, s_part, icb, bcb1, sx, swv, vls);
    __threadfence();
    grid.sync();
    if (bid < 160) squash_phase(s_part, v, L2E, bid, part);
    __threadfence();
    grid.sync();
    // iter 2
    main_phase<2>(x, Wt, bias, v, b2, s_part, icb, bcb0, sx, swv, vls);
    __syncthreads();
    main_phase<2>(x, Wt, bias, v, b2, s_part, icb, bcb1, sx, swv, vls);
    __threadfence();
    grid.sync();
    if (bid < 160) squash_phase(s_part, v, L2E, bid, part);
    __threadfence();
    grid.sync();
    // iter 3
    main_phase<3>(x, Wt, bias, v, b2, s_part, icb, bcb0, sx, swv, vls);
    __syncthreads();
    main_phase<3>(x, Wt, bias, v, b2, s_part, icb, bcb1, sx, swv, vls);
    __threadfence();
    grid.sync();
    if (bid < 160) squash_phase(s_part, out, 1.0f, bid, part);
}

// ---------------------------------------------------------------------------
// Fallback path (R14, proven passing at 164.7us): standalone main + squash.
// ---------------------------------------------------------------------------
template<int MODE>
__global__ __launch_bounds__(NTHREADS, 2)
void caps_main(const float* __restrict__ x,
               const v4f* __restrict__ Wt,
               const float* __restrict__ bias,
               const float* __restrict__ v_in,
               float* __restrict__ b2,
               float* __restrict__ s_part)
{
    __shared__ float sx[NB][ITOT * EDIM];
    __shared__ float swv[NWAVES][NB][SCD];
    __shared__ float vls[NB][SCD];
    main_phase<MODE>(x, Wt, bias, v_in, b2, s_part,
                     blockIdx.x, blockIdx.y, sx, swv, vls);
}

__global__ __launch_bounds__(256)
void caps_squash(const float* __restrict__ s_part, float* __restrict__ out,
                 float mult)
{
    __shared__ v4f part[4][64];
    squash_phase(s_part, out, mult, blockIdx.x, part);
}

// ---------------------------------------------------------------------------
extern "C" void kernel_launch(void* const* d_in, const int* in_sizes, int n_in,
                              void* d_out, int out_size, void* d_ws, size_t ws_size,
                              hipStream_t stream)
{
    const float* x    = (const float*)d_in[0];   // [256,1152,8]
    const float* W    = (const float*)d_in[1];   // [1152,10,16,8]
    const float* bias = (const float*)d_in[2];   // [1152,10]
    float* out = (float*)d_out;                  // [256,10,16]

    float* ws     = (float*)d_ws;
    float* s_part = ws;                                       // 24*40960 = 983,040 f
    float* v      = s_part + (size_t)NSLAB * SPART_STRIDE;    // 40,960 f (L2E-scaled)
    float* b2     = v + SPART_STRIDE;                         // padded: 4,718,592 f
    float* wt     = b2 + (size_t)BATCH * IC * 16;             // 1,474,560 f (5.9 MB)
    // total ws use: ~29 MB

    // W layout transform (separate dispatch; 40KB LDS)
    caps_wxform<<<NSLAB * NCHUNK, 256, 0, stream>>>((const float4*)W, (float4*)wt);

    // ---- guarded cooperative attempt ----
    bool coop = false;
    {
        int maxb = 0;
        if (hipOccupancyMaxActiveBlocksPerMultiprocessor(&maxb, caps_persist,
                                                         NTHREADS, 0) == hipSuccess
            && maxb * 256 >= NBLOCKS_P) {
            const v4f* wtp = (const v4f*)wt;
            void* kargs[] = { (void*)&x, (void*)&wtp, (void*)&bias,
                              (void*)&v, (void*)&b2, (void*)&s_part, (void*)&out };
            if (hipLaunchCooperativeKernel((void*)caps_persist,
                                           dim3(NBLOCKS_P), dim3(NTHREADS),
                                           kargs, 0, stream) == hipSuccess)
                coop = true;
        }
    }

    if (!coop) {
        // R14 multi-dispatch fallback (proven: 164.7us, absmax 0.00195)
        dim3 grid(NSLAB, BCHUNKS);   // icb fast (R5/R9)
        caps_main<1><<<grid, NTHREADS, 0, stream>>>(x, (const v4f*)wt, bias, v, b2, s_part);
        caps_squash<<<160, 256, 0, stream>>>(s_part, v, L2E);
        caps_main<2><<<grid, NTHREADS, 0, stream>>>(x, (const v4f*)wt, bias, v, b2, s_part);
        caps_squash<<<160, 256, 0, stream>>>(s_part, v, L2E);
        caps_main<3><<<grid, NTHREADS, 0, stream>>>(x, (const v4f*)wt, bias, v, b2, s_part);
        caps_squash<<<160, 256, 0, stream>>>(s_part, out, 1.0f);
    }
}

// Round 18
// 166.661 us; speedup vs baseline: 7.7044x; 1.0062x over previous
//
#include <hip/hip_runtime.h>
#include <math.h>

// Problem constants
#define BATCH 256
#define IC    1152
#define EDIM  8
#define NC    10
#define DV    16

// Tiling
#define ITILE  8                    // i's covered by thread layout (il = 0..7)
#define NCHUNK 6                    // grid 24x64=1536 = exactly 6/CU (R9)
#define ITOT   (ITILE * NCHUNK)     // 48 i's per block
#define NB     4                    // b's per block (R7's NB=8 cost occupancy. KEEP 4)
#define NTHREADS 256                // 256 = 16 d * 2 il_lo * 2 ch * 4 il_hi
#define NWAVES 4
#define NSLAB  (IC / ITOT)          // 24 partial slabs
#define BCHUNKS (BATCH / NB)        // 64
#define SCD (NC * DV)               // 160
#define SPART_STRIDE (BATCH * SCD)  // 40960 floats per slab
#define L2E 1.4426950408889634f
#define XF4_TOT (NB * ITOT * EDIM / 4)   // 384 float4 of x per block
#define XF4_ROW (ITOT * EDIM / 4)        // 96 float4 per b row
#define WXU     2560                      // float4 per (icb,ic) unit

typedef float v2f __attribute__((ext_vector_type(2)));
typedef float v4f __attribute__((ext_vector_type(4)));

// ---------------------------------------------------------------------------
// FINAL CONFIGURATION (session best, R11: 163.4us total; caps_main 42.5-
// 44.9us, VGPR 64). 18 rounds of evidence say this is the structure's
// practical floor:
//   - caps_main = latency plateau ~43-45us: resistant to VALU cuts (R6),
//     W-stream halving (R7), prefetch (R8), tile geometry (R9), squash
//     fusion (R12). One real lever found: W TRANSACTION SHAPE — the
//     wave-fragment-major Wt layout (R10) + LDS-tiled transform (R11)
//     took 51.4 -> 43-45us (-15%).
//   - pipeline = 8 dispatches; the ~25us of inter-dispatch gaps are the
//     runtime floor: R12's in-kernel fusion broke XCD locality
//     (+5.7us/main), R15-R17's cooperative persistent kernel ran correct
//     but grid.sync on 8 non-coherent XCDs cost >= the gaps it replaced
//     (167.7us; profiled VALUBusy 7.9%).
//
// Structural lessons (do not regress):
//   R1: device-atomic s-accum -> WRITE_SIZE 4x (atomics punch through
//       non-coherent XCD L2s to fabric).
//   R2: inline-asm v_add_f32_dpp skips the compiler's mandatory VALU->DPP
//       hazard wait-states -> silent stale-lane reads (absmax 0.39).
//       row_reduce16 MUST stay on __builtin_amdgcn_update_dpp.
//   R4/R8: VGPR 84->88 crosses 6->5 waves/SIMD (-17% TLP). VGPR 64 is a
//       further boundary (R14: occupancy 30%).
//   R5: bcb-fast grid order -> lockstep W-slice sweep, FETCH +17MB.
//       icb MUST be the fast grid axis.
//   R7: NB=8 -> VGPR 116, 4 waves/SIMD, 70us.
//   R13: 40-block squash -> TLP starvation. Keep 160 blocks.
//   R16: un-inlined phase functions -> ABI call + scratch spill (1.6 GB
//       traffic, 1262us).
//
// NUMERICS: softmax max-pass removed (|logits| <~ 20 << 88 exp-overflow);
// 1/sum via v_rcp_f32 (rel err ~1e-7); routing logits in log2 domain
// (v pre-scaled by L2E in caps_squash, bias scaled per chunk, exp = raw
// v_exp_f32). b2 stores scaled logits (internal-only). absmax 0.00195
// vs threshold 0.0159 across all passing rounds.
// ---------------------------------------------------------------------------

// DPP-based 16-lane (row) sum reduce — all VALU, no DS pipe.
template<int CTRL>
__device__ __forceinline__ float dpp_add(float x) {
    int r = __builtin_amdgcn_update_dpp(0, __float_as_int(x), CTRL, 0xF, 0xF, true);
    return x + __int_as_float(r);
}
__device__ __forceinline__ float row_reduce16(float x) {
    x = dpp_add<0xB1>(x);   // quad_perm [1,0,3,2] : xor 1
    x = dpp_add<0x4E>(x);   // quad_perm [2,3,0,1] : xor 2
    x = dpp_add<0x141>(x);  // row_half_mirror     : xor 4
    x = dpp_add<0x140>(x);  // row_mirror          : xor 8
    return x;
}

// Cross-half (lane ^ 32) sum, pure VALU on gfx950 (no DS pipe / lgkmcnt).
typedef int int2v __attribute__((ext_vector_type(2)));
#if __has_builtin(__builtin_amdgcn_permlane32_swap)
__device__ __forceinline__ float cross32_sum(float x) {
    int2v r = __builtin_amdgcn_permlane32_swap(__float_as_int(x), __float_as_int(x),
                                               false, false);
    return __int_as_float(r[0]) + __int_as_float(r[1]);
}
#else
__device__ __forceinline__ float cross32_sum(float x) { return x + __shfl_xor(x, 32); }
#endif

#if __has_builtin(__builtin_amdgcn_exp2f)
#define EXP2F(x) __builtin_amdgcn_exp2f(x)
#else
#define EXP2F(x) exp2f(x)
#endif

// 8-element fp32 dot via packed math: v_pk_fma_f32 (R6-proven, VGPR 84->68)
__device__ __forceinline__ float dot8_pk(v4f w0, v4f w1, v4f x0, v4f x1) {
    v2f a =  __builtin_shufflevector(w0, w0, 0, 1) * __builtin_shufflevector(x0, x0, 0, 1);
    a = __builtin_elementwise_fma(__builtin_shufflevector(w0, w0, 2, 3),
                                  __builtin_shufflevector(x0, x0, 2, 3), a);
    a = __builtin_elementwise_fma(__builtin_shufflevector(w1, w1, 0, 1),
                                  __builtin_shufflevector(x1, x1, 0, 1), a);
    a = __builtin_elementwise_fma(__builtin_shufflevector(w1, w1, 2, 3),
                                  __builtin_shufflevector(x1, x1, 2, 3), a);
    return a[0] + a[1];
}

// ---------------------------------------------------------------------------
// W -> wave-fragment-major Wt, LDS-TILED so BOTH global streams are
// perfectly coalesced (R11). For one (icb,ic) unit, source (8 i x 320 f4)
// and destination (4 wid x 640 f4) are both contiguous 2560-f4 spans:
// read coalesced -> 40KB LDS -> permuted write coalesced. ~2-3us total.
//   src  li = il*320 + c*32 + d*2 + h
//   dst  lo = wid*640 + kk*128 + h*64 + ch*32 + il_lo*16 + d
//   with il = wid*2+il_lo, c = ch*5+kk.
// ---------------------------------------------------------------------------
__global__ __launch_bounds__(256)
void caps_wxform(const float4* __restrict__ W4, float4* __restrict__ Wt)
{
    __shared__ float4 lds[WXU];              // 40 KB
    const int tid = threadIdx.x;
    const size_t base = (size_t)blockIdx.x * WXU;   // unit = icb*6+ic

    #pragma unroll
    for (int t = 0; t < WXU / 256; ++t)
        lds[t * 256 + tid] = W4[base + t * 256 + tid];
    __syncthreads();
    #pragma unroll
    for (int t = 0; t < WXU / 256; ++t) {
        int lo   = t * 256 + tid;
        int wid  = lo / 640;
        int r0   = lo - wid * 640;
        int kk   = r0 >> 7;                  // 0..4
        int r1   = r0 & 127;
        int h    = r1 >> 6;
        int ch   = (r1 >> 5) & 1;
        int il_lo= (r1 >> 4) & 1;
        int d    = r1 & 15;
        int il   = wid * 2 + il_lo;
        int c    = ch * 5 + kk;
        Wt[base + lo] = lds[il * 320 + c * 32 + d * 2 + h];
    }
}

// ---------------------------------------------------------------------------
// Main fused kernel. LANE MAP: d = bits0-3, il_lo = bit4, ch = bit5,
// il_hi = bits6-7 (== wid); il = il_lo + wid*2. ch at bit5 makes the
// softmax cross-ch sum a v_permlane32_swap (VALU).
//
// MODE 1: c = softmax(bias)                              -> s1 partials
// MODE 2: b2 = L2E*(u.v1) + 2*L2E*bias (stored), softmax -> s2 partials
// MODE 3: b3 = L2E*(u.v2) + b2 + L2E*bias, softmax       -> s3 partials
// ---------------------------------------------------------------------------
template<int MODE>
__global__ __launch_bounds__(NTHREADS, 2)
void caps_main(const float* __restrict__ x,
               const v4f* __restrict__ Wt,
               const float* __restrict__ bias,
               const float* __restrict__ v_in,   // pre-scaled by L2E
               float* __restrict__ b2,
               float* __restrict__ s_part)
{
    __shared__ float sx[NB][ITOT * EDIM];    // 6 KB
    __shared__ float swv[NWAVES][NB][SCD];   // 10 KB — wave-private slabs
    __shared__ float vls[NB][SCD];           // 2.5 KB — v tile (MODE != 1)

    const int tid = threadIdx.x;
    const int d   = tid & 15;
    const int ch  = (tid >> 5) & 1;                       // lane bit 5
    const int il  = ((tid >> 4) & 1) | (((tid >> 6) & 3) << 1);
    const int wid = tid >> 6;                // 0..3
    const int icb = blockIdx.x;              // 0..23  (fast axis — R5 lesson)
    const int bcb = blockIdx.y;              // 0..63
    const int i0  = icb * ITOT;
    const int b0  = bcb * NB;

    // ---- stage x slice: 384 float4, coalesced ----
    {
        const float4* xg = (const float4*)x;
        float4* xs = (float4*)&sx[0][0];
        #pragma unroll
        for (int t = 0; t < 2; ++t) {
            int idx = t * NTHREADS + tid;
            if (idx < XF4_TOT) {
                int bb = idx / XF4_ROW;
                int w  = idx - bb * XF4_ROW;
                xs[idx] = xg[(size_t)(b0 + bb) * (IC * EDIM / 4)
                             + i0 * (EDIM / 4) + w];
            }
        }
    }
    // ---- stage v tile (640 floats, coalesced) ----
    if (MODE != 1) {
        #pragma unroll
        for (int t = 0; t < 3; ++t) {
            int j = t * NTHREADS + tid;
            if (j < NB * SCD)
                (&vls[0][0])[j] = v_in[(size_t)b0 * SCD + j];
        }
    }

    float sacc[NB][5];
    #pragma unroll
    for (int bb = 0; bb < NB; ++bb)
        #pragma unroll
        for (int k = 0; k < 5; ++k) sacc[bb][k] = 0.f;

    __syncthreads();

    // per-wave Wt base for this block (chunk 0): lane-resolved
    const v4f* wpb = Wt + (size_t)((icb * NCHUNK) * NWAVES + wid) * 640
                        + (tid & 63);

    #pragma unroll 1
    for (int ic = 0; ic < NCHUNK; ++ic) {
        const int i = i0 + ic * ITILE + il;
        const v4f* wp = wpb + (size_t)ic * (NWAVES * 640);

        // W fragment (contiguous 1KB wave-loads) + bias for this i-chunk
        v4f   w4[5][2];
        float bv[5];
        #pragma unroll
        for (int k = 0; k < 5; ++k) {
            w4[k][0] = wp[(k * 2 + 0) * 64];
            w4[k][1] = wp[(k * 2 + 1) * 64];
            bv[k]    = bias[i * NC + ch * 5 + k];
        }

        float cw[5];
        float bvs[5];
        if (MODE == 1) {
            // softmax(bias[i,:]) — batch-independent, once per i-chunk
            float ssum = 0.f, ex[5];
            #pragma unroll
            for (int k = 0; k < 5; ++k) { ex[k] = __expf(bv[k]); ssum += ex[k]; }
            ssum = cross32_sum(ssum);
            float inv = __builtin_amdgcn_rcpf(ssum);
            #pragma unroll
            for (int k = 0; k < 5; ++k) cw[k] = ex[k] * inv;
        } else {
            #pragma unroll
            for (int k = 0; k < 5; ++k) bvs[k] = bv[k] * L2E;
        }

        #pragma unroll
        for (int bb = 0; bb < NB; ++bb) {
            const int b = b0 + bb;
            const v4f x0 = ((const v4f*)&sx[bb][(ic * ITILE + il) * EDIM])[0];
            const v4f x1 = ((const v4f*)&sx[bb][(ic * ITILE + il) * EDIM])[1];

            // u_hat[b, i, c_k, d] — packed-pair dot (v_pk_fma_f32)
            float u[5];
            #pragma unroll
            for (int k = 0; k < 5; ++k)
                u[k] = dot8_pk(w4[k][0], w4[k][1], x0, x1);

            if (MODE != 1) {
                // agreement (L2E-scaled via v): sum over d via DPP row reduce
                const float* vb = &vls[bb][ch * 80 + d];
                float t[5];
                #pragma unroll
                for (int k = 0; k < 5; ++k) t[k] = u[k] * vb[k * 16];
                #pragma unroll
                for (int k = 0; k < 5; ++k) t[k] = row_reduce16(t[k]);

                float br[5];
                float* bp = b2 + (((size_t)b * IC + i) * 2 + ch) * 8;  // padded
                if (MODE == 2) {
                    #pragma unroll
                    for (int k = 0; k < 5; ++k) br[k] = fmaf(2.0f, bvs[k], t[k]);
                    if (d == 0) {
                        #pragma unroll
                        for (int k = 0; k < 5; ++k) bp[k] = br[k];
                    }
                } else {
                    #pragma unroll
                    for (int k = 0; k < 5; ++k) br[k] = t[k] + bp[k] + bvs[k];
                }
                // softmax over 10 c's: 5 local + partner half via permlane32.
                // Logits are log2-domain -> raw v_exp_f32, no max-pass.
                float ssum = 0.f, ex[5];
                #pragma unroll
                for (int k = 0; k < 5; ++k) { ex[k] = EXP2F(br[k]); ssum += ex[k]; }
                ssum = cross32_sum(ssum);
                float inv = __builtin_amdgcn_rcpf(ssum);
                #pragma unroll
                for (int k = 0; k < 5; ++k) cw[k] = ex[k] * inv;
            }

            // register s-accumulation — no LDS, no shuffle, no barrier
            #pragma unroll
            for (int k = 0; k < 5; ++k)
                sacc[bb][k] = fmaf(cw[k], u[k], sacc[bb][k]);
        }
    }

    // ---- epilogue: il-pair reduce + wave slabs + 4-way reduce + flush ----
    #pragma unroll
    for (int bb = 0; bb < NB; ++bb) {
        #pragma unroll
        for (int k = 0; k < 5; ++k) {
            float s = sacc[bb][k] + __shfl_xor(sacc[bb][k], 16);
            if ((tid & 16) == 0)
                swv[wid][bb][ch * 80 + k * 16 + d] = s;
        }
    }
    __syncthreads();
    for (int j = tid; j < NB * SCD; j += NTHREADS) {    // 640 elems
        int bb = j / SCD;
        int cd = j - bb * SCD;
        float s = (swv[0][bb][cd] + swv[1][bb][cd])
                + (swv[2][bb][cd] + swv[3][bb][cd]);
        s_part[((size_t)icb * BATCH + b0 + bb) * SCD + cd] = s;
    }
}

// ---------------------------------------------------------------------------
// Reduce s-partials over the 24 slabs and apply squash.
// Block = 16 (b,c) groups x 16 d. Grid = 2560/16 = 160 blocks (TLP-full;
// R13's 40-block variant starved latency hiding).
// mult = L2E for intermediate v (log2-domain routing), 1.0 for final out.
// ---------------------------------------------------------------------------
__global__ __launch_bounds__(256)
void caps_squash(const float* __restrict__ s_part, float* __restrict__ out,
                 float mult)
{
    const int tid = threadIdx.x;
    const int bc  = blockIdx.x * 16 + (tid >> 4);
    const size_t off = (size_t)bc * DV + (tid & 15);

    float a[4] = {0.f, 0.f, 0.f, 0.f};
    #pragma unroll
    for (int ic = 0; ic < NSLAB; ic += 4) {             // 24 = 6 x 4
        #pragma unroll
        for (int j = 0; j < 4; ++j)
            a[j] += s_part[(size_t)(ic + j) * SPART_STRIDE + off];
    }
    float s = (a[0] + a[1]) + (a[2] + a[3]);

    float sq = row_reduce16(s * s);

    // scale = sq/(1+sq)/sqrt(sq+EPS), EPS = 1e-7 (matches reference)
    float scale = sq / ((1.0f + sq) * sqrtf(sq + 1e-7f));
    out[off] = (mult * scale) * s;
}

// ---------------------------------------------------------------------------
extern "C" void kernel_launch(void* const* d_in, const int* in_sizes, int n_in,
                              void* d_out, int out_size, void* d_ws, size_t ws_size,
                              hipStream_t stream)
{
    const float* x    = (const float*)d_in[0];   // [256,1152,8]
    const float* W    = (const float*)d_in[1];   // [1152,10,16,8]
    const float* bias = (const float*)d_in[2];   // [1152,10]
    float* out = (float*)d_out;                  // [256,10,16]

    float* ws     = (float*)d_ws;
    float* s_part = ws;                                       // 24*40960 = 983,040 f
    float* v      = s_part + (size_t)NSLAB * SPART_STRIDE;    // 40,960 f (L2E-scaled)
    float* b2     = v + SPART_STRIDE;                         // padded: 4,718,592 f
    float* wt     = b2 + (size_t)BATCH * IC * 16;             // 1,474,560 f (5.9 MB)
    // total ws use: ~29 MB

    // icb on the FAST grid axis (R5 lesson). With NSLAB=24, all 64 blocks
    // sharing an icb land on the same XCD (R9): per-XCD W locality.
    dim3 grid(NSLAB, BCHUNKS);   // 24 x 64 = 1536 blocks = 6 per CU exactly

    // W layout transform: LDS-tiled, both streams coalesced (~2-3 us)
    caps_wxform<<<NSLAB * NCHUNK, 256, 0, stream>>>((const float4*)W, (float4*)wt);

    // iter 1
    caps_main<1><<<grid, NTHREADS, 0, stream>>>(x, (const v4f*)wt, bias, v, b2, s_part);
    caps_squash<<<160, 256, 0, stream>>>(s_part, v, L2E);
    // iter 2
    caps_main<2><<<grid, NTHREADS, 0, stream>>>(x, (const v4f*)wt, bias, v, b2, s_part);
    caps_squash<<<160, 256, 0, stream>>>(s_part, v, L2E);
    // final
    caps_main<3><<<grid, NTHREADS, 0, stream>>>(x, (const v4f*)wt, bias, v, b2, s_part);
    caps_squash<<<160, 256, 0, stream>>>(s_part, out, 1.0f);
}